// Round 1
// baseline (31467.957 us; speedup 1.0000x reference)
//
#include <hip/hip_runtime.h>
#include <stdint.h>

#define Bsz 256
#define Tt 128
#define OBSd 768
#define ACTd 7
#define DETERd 512
#define TOTd 1024
#define OUTFd 3584                 // 512 + 1024 + 1024 + 1024
#define OUT_ROW (Tt * OUTFd)       // 458752 floats per batch row

// ---------------------------------------------------------------------------
// Threefry-2x32, exact JAX semantics
// ---------------------------------------------------------------------------
__device__ __forceinline__ uint32_t rotl32(uint32_t v, int r) {
  return (v << r) | (v >> (32 - r));
}

__device__ __forceinline__ void tf2x32(uint32_t key0, uint32_t key1,
                                       uint32_t x0, uint32_t x1,
                                       uint32_t& o0, uint32_t& o1) {
  uint32_t ks0 = key0, ks1 = key1, ks2 = key0 ^ key1 ^ 0x1BD11BDAu;
  x0 += ks0; x1 += ks1;
#define TFR(r) { x0 += x1; x1 = rotl32(x1, (r)); x1 ^= x0; }
  TFR(13) TFR(15) TFR(26) TFR(6)
  x0 += ks1; x1 += ks2 + 1u;
  TFR(17) TFR(29) TFR(16) TFR(24)
  x0 += ks2; x1 += ks0 + 2u;
  TFR(13) TFR(15) TFR(26) TFR(6)
  x0 += ks0; x1 += ks1 + 3u;
  TFR(17) TFR(29) TFR(16) TFR(24)
  x0 += ks1; x1 += ks2 + 4u;
  TFR(13) TFR(15) TFR(26) TFR(6)
  x0 += ks2; x1 += ks0 + 5u;
#undef TFR
  o0 = x0; o1 = x1;
}

// keys[t] = threefry((0,42), (0, t)) both words  (partitionable fold-like split)
__global__ __launch_bounds__(128) void keys_k(uint32_t* keys) {
  const int t = threadIdx.x;
  uint32_t o0, o1;
  tf2x32(0u, 42u, 0u, (uint32_t)t, o0, o1);
  keys[2 * t] = o0;
  keys[2 * t + 1] = o1;
}

// ---------------------------------------------------------------------------
// Generic f64 GEMM: C[M,N] = [A_f64 | A2_f32] @ W_f32 + bias, optional ELU.
// M=256 fixed. 32x32 tile / block, 256 threads, 2x2 per thread, KC=16.
// Two configs fused via blockIdx.z.
// ---------------------------------------------------------------------------
struct GemmCfg {
  const double* A;  int lda;    // f64 part, columns [0, K1)
  const float* A2;  int lda2;   // f32 tail, columns [K1, K)
  int K1, K, N;
  const float* W;               // [K, N] row-major
  const float* bias;            // [N]
  double* outD; int ldoD;       // optional f64 out
  float*  outF; int ldoF;       // optional f32 out (into d_out)
  int elu;
};

__global__ __launch_bounds__(256) void gemm_f64(GemmCfg c0, GemmCfg c1) {
  GemmCfg c = blockIdx.z ? c1 : c0;
  __shared__ double As[16][34];   // [kk][m], padded
  __shared__ double Ws[16][32];   // [kk][n]
  const int tid = threadIdx.x;
  const int tx = tid & 15, ty = tid >> 4;
  const int row0 = blockIdx.y * 32;
  const int col0 = blockIdx.x * 32;
  double a00 = 0.0, a01 = 0.0, a10 = 0.0, a11 = 0.0;
  const int nk = (c.K + 15) >> 4;
  const int sA = tid * 2;
  const int kkA = sA & 15, mA = sA >> 4;   // A staging: 2 consecutive k of one row
  const int kkW = sA >> 5, nW = sA & 31;   // W staging: 2 consecutive n of one k-row
  for (int kt = 0; kt < nk; ++kt) {
    const int k0 = kt << 4;
    {
      const int gr = row0 + mA;
      const int gc = k0 + kkA;
      double v0 = 0.0, v1 = 0.0;
      if (gc < c.K1)          v0 = c.A[gr * c.lda + gc];
      else if (gc < c.K)      v0 = (double)c.A2[gr * c.lda2 + (gc - c.K1)];
      if (gc + 1 < c.K1)      v1 = c.A[gr * c.lda + gc + 1];
      else if (gc + 1 < c.K)  v1 = (double)c.A2[gr * c.lda2 + (gc + 1 - c.K1)];
      As[kkA][mA] = v0;
      As[kkA + 1][mA] = v1;
    }
    {
      const int gk = k0 + kkW;
      float wx = 0.f, wy = 0.f;
      if (gk < c.K) {
        const float2 wv = *(const float2*)(c.W + (size_t)gk * c.N + col0 + nW);
        wx = wv.x; wy = wv.y;
      }
      Ws[kkW][nW] = (double)wx;
      Ws[kkW][nW + 1] = (double)wy;
    }
    __syncthreads();
#pragma unroll
    for (int kk = 0; kk < 16; ++kk) {
      const double av0 = As[kk][2 * ty], av1 = As[kk][2 * ty + 1];
      const double bv0 = Ws[kk][2 * tx], bv1 = Ws[kk][2 * tx + 1];
      a00 = fma(av0, bv0, a00);
      a01 = fma(av0, bv1, a01);
      a10 = fma(av1, bv0, a10);
      a11 = fma(av1, bv1, a11);
    }
    __syncthreads();
  }
  const int r0 = row0 + 2 * ty;
  const int cc = col0 + 2 * tx;
  const double b0 = (double)c.bias[cc], b1 = (double)c.bias[cc + 1];
  double v00 = a00 + b0, v01 = a01 + b1, v10 = a10 + b0, v11 = a11 + b1;
  if (c.elu) {
    v00 = v00 > 0.0 ? v00 : expm1(v00);
    v01 = v01 > 0.0 ? v01 : expm1(v01);
    v10 = v10 > 0.0 ? v10 : expm1(v10);
    v11 = v11 > 0.0 ? v11 : expm1(v11);
  }
  if (c.outD) {
    double* o = c.outD + (size_t)r0 * c.ldoD + cc;
    o[0] = v00; o[1] = v01;
    o[c.ldoD] = v10; o[c.ldoD + 1] = v11;
  }
  if (c.outF) {
    float* o = c.outF + (size_t)r0 * c.ldoF + cc;
    o[0] = (float)v00; o[1] = (float)v01;
    o[c.ldoF] = (float)v10; o[c.ldoF + 1] = (float)v11;
  }
}

// ---------------------------------------------------------------------------
// GRU gate combine: r,z,n -> deter update; writes deter feature block of out.
// ---------------------------------------------------------------------------
__global__ __launch_bounds__(256) void gates_k(const double* __restrict__ gi,
                                               const double* __restrict__ gh,
                                               double* __restrict__ deter,
                                               float* __restrict__ outD) {
  const int i = blockIdx.x * 256 + threadIdx.x;   // 256*512 elements
  const int b = i >> 9, j = i & 511;
  const double* gib = gi + b * 1536;
  const double* ghb = gh + b * 1536;
  const double ir = gib[j], iz = gib[512 + j], inn = gib[1024 + j];
  const double hr = ghb[j], hz = ghb[512 + j], hn = ghb[1024 + j];
  const double r = 1.0 / (1.0 + exp(-(ir + hr)));
  const double z = 1.0 / (1.0 + exp(-(iz + hz)));
  const double n = tanh(inn + r * hn);
  const int di = b * 512 + j;
  const double d = (1.0 - z) * n + z * deter[di];
  deter[di] = d;
  outD[(size_t)b * OUT_ROW + j] = (float)d;
}

// ---------------------------------------------------------------------------
// Softmax + Gumbel-argmax sampling (exact JAX partitionable threefry bits) +
// straight-through stoch; writes stoch feature block of out.
// One thread per (b, s) row of 32 classes.
// ---------------------------------------------------------------------------
__global__ __launch_bounds__(256) void sample_k(const double* __restrict__ logits,
                                                const uint32_t* __restrict__ keys,
                                                int t,
                                                double* __restrict__ stoch,
                                                float* __restrict__ outS) {
  const int i = blockIdx.x * 256 + threadIdx.x;   // 8192 = 256*32
  const int b = i >> 5, s = i & 31;
  const uint32_t k0 = keys[2 * t], k1 = keys[2 * t + 1];
  const double* lrow = logits + b * 1024 + s * 32;
  const uint32_t jbase = (uint32_t)(b * 1024 + s * 32);

  double ml = -1.0e300, best = -1.0e300;
  int bestc = 0;
  for (int cI = 0; cI < 32; ++cI) {
    const double l = lrow[cI];
    if (l > ml) ml = l;
    uint32_t o0, o1;
    tf2x32(k0, k1, 0u, jbase + (uint32_t)cI, o0, o1);
    const uint32_t bits = o0 ^ o1;                 // partitionable 32-bit path
    const uint32_t m = bits >> 9;
    const float uf = __uint_as_float(m | 0x3f800000u) - 1.0f;
    const double u = (m == 0u) ? (double)1.17549435e-38f : (double)uf;
    const double g = -log(-log(u));                // standard gumbel
    const double v = g + l;
    if (v > best) { best = v; bestc = cI; }        // strict > : first-index ties
  }
  double se = 0.0;
  for (int cI = 0; cI < 32; ++cI) se += exp(lrow[cI] - ml);
  double* srow = stoch + b * 1024 + s * 32;
  float* orow = outS + (size_t)b * OUT_ROW + s * 32;
  for (int cI = 0; cI < 32; ++cI) {
    const double p = exp(lrow[cI] - ml) / se;
    const double sv = (cI == bestc) ? 1.0 : 0.0;
    const double ov = (sv + p) - p;                // straight-through forward
    srow[cI] = ov;
    orow[cI] = (float)ov;
  }
}

// ---------------------------------------------------------------------------
extern "C" void kernel_launch(void* const* d_in, const int* in_sizes, int n_in,
                              void* d_out, int out_size, void* d_ws, size_t ws_size,
                              hipStream_t stream) {
  const float* obs  = (const float*)d_in[0];
  const float* act  = (const float*)d_in[1];
  const float* w_ih = (const float*)d_in[2];
  const float* w_hh = (const float*)d_in[3];
  const float* b_ih = (const float*)d_in[4];
  const float* b_hh = (const float*)d_in[5];
  const float* pw1  = (const float*)d_in[6];
  const float* pb1  = (const float*)d_in[7];
  const float* pw2  = (const float*)d_in[8];
  const float* pb2  = (const float*)d_in[9];
  const float* qw1  = (const float*)d_in[10];
  const float* qb1  = (const float*)d_in[11];
  const float* qw2  = (const float*)d_in[12];
  const float* qb2  = (const float*)d_in[13];
  float* out = (float*)d_out;
  char* ws = (char*)d_ws;

  // workspace layout (bytes)
  double*   deter = (double*)(ws + 0);          // 256*512*8   = 1 MiB
  double*   stoch = (double*)(ws + 1048576);    // 256*1024*8  = 2 MiB
  double*   gi    = (double*)(ws + 3145728);    // 256*1536*8  = 3 MiB
  double*   gh    = (double*)(ws + 6291456);    // 3 MiB
  double*   h1pr  = (double*)(ws + 9437184);    // 1 MiB
  double*   h1po  = (double*)(ws + 10485760);   // 1 MiB
  double*   plog  = (double*)(ws + 11534336);   // 2 MiB
  uint32_t* keys  = (uint32_t*)(ws + 13631488); // 1 KiB

  hipMemsetAsync(deter, 0, 256 * 512 * 8, stream);
  hipMemsetAsync(stoch, 0, 256 * 1024 * 8, stream);
  keys_k<<<1, 128, 0, stream>>>(keys);

  for (int t = 0; t < Tt; ++t) {
    // GRU input/hidden matmuls (z-fused)
    GemmCfg cgi { stoch, 1024, act + (size_t)t * ACTd, Tt * ACTd, 1024, 1031, 1536,
                  w_ih, b_ih, gi, 1536, nullptr, 0, 0 };
    GemmCfg cgh { deter, 512, nullptr, 0, 512, 512, 1536,
                  w_hh, b_hh, gh, 1536, nullptr, 0, 0 };
    gemm_f64<<<dim3(48, 8, 2), 256, 0, stream>>>(cgi, cgh);

    gates_k<<<512, 256, 0, stream>>>(gi, gh, deter, out + (size_t)t * OUTFd);

    // prior / posterior first layers (ELU fused, z-fused)
    GemmCfg cp1 { deter, 512, nullptr, 0, 512, 512, 512,
                  pw1, pb1, h1pr, 512, nullptr, 0, 1 };
    GemmCfg cq1 { deter, 512, obs + (size_t)t * OBSd, Tt * OBSd, 512, 1280, 512,
                  qw1, qb1, h1po, 512, nullptr, 0, 1 };
    gemm_f64<<<dim3(16, 8, 2), 256, 0, stream>>>(cp1, cq1);

    // prior / posterior logits (z-fused); prior straight to out, post also to ws
    GemmCfg cp2 { h1pr, 512, nullptr, 0, 512, 512, 1024,
                  pw2, pb2, nullptr, 0, out + (size_t)t * OUTFd + 1536, OUT_ROW, 0 };
    GemmCfg cq2 { h1po, 512, nullptr, 0, 512, 512, 1024,
                  qw2, qb2, plog, 1024, out + (size_t)t * OUTFd + 2560, OUT_ROW, 0 };
    gemm_f64<<<dim3(32, 8, 2), 256, 0, stream>>>(cp2, cq2);

    sample_k<<<32, 256, 0, stream>>>(plog, keys, t, stoch,
                                     out + (size_t)t * OUTFd + 512);
  }
}

// Round 2
// 22810.716 us; speedup vs baseline: 1.3795x; 1.3795x over previous
//
#include <hip/hip_runtime.h>
#include <stdint.h>

#define Tt 128
#define OBSd 768
#define ACTd 7
#define OUTFd 3584                 // 512 deter + 1024 stoch + 1024 prior + 1024 post
#define OUT_ROW (Tt * OUTFd)       // floats per batch row
#define TC 16                      // prior batch chunk (timesteps)

// ---------------------------------------------------------------------------
// Threefry-2x32, exact JAX semantics (identical to round-1 — do not touch)
// ---------------------------------------------------------------------------
__device__ __forceinline__ uint32_t rotl32(uint32_t v, int r) {
  return (v << r) | (v >> (32 - r));
}

__device__ __forceinline__ void tf2x32(uint32_t key0, uint32_t key1,
                                       uint32_t x0, uint32_t x1,
                                       uint32_t& o0, uint32_t& o1) {
  uint32_t ks0 = key0, ks1 = key1, ks2 = key0 ^ key1 ^ 0x1BD11BDAu;
  x0 += ks0; x1 += ks1;
#define TFR(r) { x0 += x1; x1 = rotl32(x1, (r)); x1 ^= x0; }
  TFR(13) TFR(15) TFR(26) TFR(6)
  x0 += ks1; x1 += ks2 + 1u;
  TFR(17) TFR(29) TFR(16) TFR(24)
  x0 += ks2; x1 += ks0 + 2u;
  TFR(13) TFR(15) TFR(26) TFR(6)
  x0 += ks0; x1 += ks1 + 3u;
  TFR(17) TFR(29) TFR(16) TFR(24)
  x0 += ks1; x1 += ks2 + 4u;
  TFR(13) TFR(15) TFR(26) TFR(6)
  x0 += ks2; x1 += ks0 + 5u;
#undef TFR
  o0 = x0; o1 = x1;
}

__global__ __launch_bounds__(128) void keys_k(uint32_t* keys) {
  const int t = threadIdx.x;
  uint32_t o0, o1;
  tf2x32(0u, 42u, 0u, (uint32_t)t, o0, o1);
  keys[2 * t] = o0;
  keys[2 * t + 1] = o1;
}

// ---------------------------------------------------------------------------
// Kernel A: fused GRU step.
//   gh = deter_prev @ w_hh (f64 GEMM, 3 gate column groups per tile)
//   gi = one-hot gather of w_ih rows (stoch) + 7-term act part
//   gates -> deter_next (f64) + f32 deter block of out
// Grid (16,8): 32x32 output tile over [256 x 512], 3 gate accumulators.
// ---------------------------------------------------------------------------
__global__ __launch_bounds__(256) void gru_k(const double* __restrict__ dprev,
                                             double* __restrict__ dnext,
                                             const int* __restrict__ sidx,
                                             const float* __restrict__ sval,
                                             const float* __restrict__ act,
                                             const float* __restrict__ w_ih,
                                             const float* __restrict__ w_hh,
                                             const float* __restrict__ b_ih,
                                             const float* __restrict__ b_hh,
                                             float* __restrict__ out, int t) {
  __shared__ double As[16][34];
  __shared__ double Wr[16][32], Wz[16][32], Wn[16][32];
  __shared__ int   sIdxL[32][32];
  __shared__ float sValL[32][32];
  __shared__ float actL[32][8];

  const int tid = threadIdx.x;
  const int tx = tid & 15, ty = tid >> 4;
  const int row0 = blockIdx.y * 32;
  const int col0 = blockIdx.x * 32;

  // stage sample indices/values + actions for this block's 32 batch rows
  {
    const int e0 = tid * 4;
    for (int i = 0; i < 4; ++i) {
      const int e = e0 + i, bl = e >> 5, s = e & 31;
      sIdxL[bl][s] = sidx[(row0 + bl) * 32 + s];
      sValL[bl][s] = sval[(row0 + bl) * 32 + s];
    }
    if (tid < 224) {
      const int bl = tid / 7, j = tid % 7;
      actL[bl][j] = act[((size_t)(row0 + bl) * Tt + t) * ACTd + j];
    }
  }

  double aR[2][2] = {}, aZ[2][2] = {}, aNi[2][2] = {}, aNh[2][2] = {};

  const int sA = tid * 2;
  const int kkA = sA & 15, mA = sA >> 4;
  const int kkW = sA >> 5, nW = sA & 31;

  for (int k0 = 0; k0 < 512; k0 += 16) {
    {
      const double2 dv = *(const double2*)(dprev + (size_t)(row0 + mA) * 512 + k0 + kkA);
      As[kkA][mA] = dv.x; As[kkA + 1][mA] = dv.y;
      const size_t wb = (size_t)(k0 + kkW) * 1536 + col0 + nW;
      float2 f;
      f = *(const float2*)(w_hh + wb);        Wr[kkW][nW] = f.x; Wr[kkW][nW + 1] = f.y;
      f = *(const float2*)(w_hh + wb + 512);  Wz[kkW][nW] = f.x; Wz[kkW][nW + 1] = f.y;
      f = *(const float2*)(w_hh + wb + 1024); Wn[kkW][nW] = f.x; Wn[kkW][nW + 1] = f.y;
    }
    __syncthreads();
#pragma unroll
    for (int kk = 0; kk < 16; ++kk) {
      const double2 av = *(const double2*)&As[kk][2 * ty];
      const double2 wr = *(const double2*)&Wr[kk][2 * tx];
      const double2 wz = *(const double2*)&Wz[kk][2 * tx];
      const double2 wn = *(const double2*)&Wn[kk][2 * tx];
      aR[0][0] = fma(av.x, wr.x, aR[0][0]); aR[0][1] = fma(av.x, wr.y, aR[0][1]);
      aR[1][0] = fma(av.y, wr.x, aR[1][0]); aR[1][1] = fma(av.y, wr.y, aR[1][1]);
      aZ[0][0] = fma(av.x, wz.x, aZ[0][0]); aZ[0][1] = fma(av.x, wz.y, aZ[0][1]);
      aZ[1][0] = fma(av.y, wz.x, aZ[1][0]); aZ[1][1] = fma(av.y, wz.y, aZ[1][1]);
      aNh[0][0] = fma(av.x, wn.x, aNh[0][0]); aNh[0][1] = fma(av.x, wn.y, aNh[0][1]);
      aNh[1][0] = fma(av.y, wn.x, aNh[1][0]); aNh[1][1] = fma(av.y, wn.y, aNh[1][1]);
    }
    __syncthreads();
  }

  // gi gather: stoch is one-hot (forward value 1.0 to within 1e-16)
  for (int rb = 0; rb < 2; ++rb) {
    const int bl = 2 * ty + rb;
    for (int s = 0; s < 32; ++s) {
      const float v = sValL[bl][s];
      if (v != 0.0f) {
        const size_t wb = (size_t)(s * 32 + sIdxL[bl][s]) * 1536 + col0 + 2 * tx;
        const float2 f0 = *(const float2*)(w_ih + wb);
        const float2 f1 = *(const float2*)(w_ih + wb + 512);
        const float2 f2 = *(const float2*)(w_ih + wb + 1024);
        const double dv = (double)v;
        aR[rb][0]  = fma(dv, (double)f0.x, aR[rb][0]);
        aR[rb][1]  = fma(dv, (double)f0.y, aR[rb][1]);
        aZ[rb][0]  = fma(dv, (double)f1.x, aZ[rb][0]);
        aZ[rb][1]  = fma(dv, (double)f1.y, aZ[rb][1]);
        aNi[rb][0] = fma(dv, (double)f2.x, aNi[rb][0]);
        aNi[rb][1] = fma(dv, (double)f2.y, aNi[rb][1]);
      }
    }
    for (int j2 = 0; j2 < 7; ++j2) {
      const double av = (double)actL[bl][j2];
      const size_t wb = (size_t)(1024 + j2) * 1536 + col0 + 2 * tx;
      const float2 f0 = *(const float2*)(w_ih + wb);
      const float2 f1 = *(const float2*)(w_ih + wb + 512);
      const float2 f2 = *(const float2*)(w_ih + wb + 1024);
      aR[rb][0]  = fma(av, (double)f0.x, aR[rb][0]);
      aR[rb][1]  = fma(av, (double)f0.y, aR[rb][1]);
      aZ[rb][0]  = fma(av, (double)f1.x, aZ[rb][0]);
      aZ[rb][1]  = fma(av, (double)f1.y, aZ[rb][1]);
      aNi[rb][0] = fma(av, (double)f2.x, aNi[rb][0]);
      aNi[rb][1] = fma(av, (double)f2.y, aNi[rb][1]);
    }
  }

  // gates
  for (int rb = 0; rb < 2; ++rb) {
    const int b = row0 + 2 * ty + rb;
    for (int cb = 0; cb < 2; ++cb) {
      const int jj = col0 + 2 * tx + cb;
      const double dold = dprev[(size_t)b * 512 + jj];
      const double xr = aR[rb][cb] + (double)b_ih[jj] + (double)b_hh[jj];
      const double xz = aZ[rb][cb] + (double)b_ih[512 + jj] + (double)b_hh[512 + jj];
      const double r = 1.0 / (1.0 + exp(-xr));
      const double z = 1.0 / (1.0 + exp(-xz));
      const double n = tanh(aNi[rb][cb] + (double)b_ih[1024 + jj] +
                            r * (aNh[rb][cb] + (double)b_hh[1024 + jj]));
      const double dn = (1.0 - z) * n + z * dold;
      dnext[(size_t)b * 512 + jj] = dn;
      out[(size_t)b * OUT_ROW + (size_t)t * OUTFd + jj] = (float)dn;
    }
  }
}

// ---------------------------------------------------------------------------
// Kernel B: h1po = ELU([deter | obs_t] @ qw1 + qb1), f64. Grid (16,8), K=1280.
// ---------------------------------------------------------------------------
__global__ __launch_bounds__(256) void post1_k(const double* __restrict__ deter,
                                               const float* __restrict__ obs,
                                               const float* __restrict__ qw1,
                                               const float* __restrict__ qb1,
                                               double* __restrict__ h1po, int t) {
  __shared__ double As[16][34];
  __shared__ double Ws[16][32];
  const int tid = threadIdx.x;
  const int tx = tid & 15, ty = tid >> 4;
  const int row0 = blockIdx.y * 32;
  const int col0 = blockIdx.x * 32;
  double a00 = 0, a01 = 0, a10 = 0, a11 = 0;
  const int sA = tid * 2;
  const int kkA = sA & 15, mA = sA >> 4;
  const int kkW = sA >> 5, nW = sA & 31;
  for (int k0 = 0; k0 < 1280; k0 += 16) {
    const int gc = k0 + kkA;
    const int gr = row0 + mA;
    if (gc < 512) {
      const double2 dv = *(const double2*)(deter + (size_t)gr * 512 + gc);
      As[kkA][mA] = dv.x; As[kkA + 1][mA] = dv.y;
    } else {
      const float2 fv = *(const float2*)(obs + ((size_t)gr * Tt + t) * OBSd + (gc - 512));
      As[kkA][mA] = (double)fv.x; As[kkA + 1][mA] = (double)fv.y;
    }
    const float2 wv = *(const float2*)(qw1 + (size_t)(k0 + kkW) * 512 + col0 + nW);
    Ws[kkW][nW] = (double)wv.x; Ws[kkW][nW + 1] = (double)wv.y;
    __syncthreads();
#pragma unroll
    for (int kk = 0; kk < 16; ++kk) {
      const double2 av = *(const double2*)&As[kk][2 * ty];
      const double2 wv2 = *(const double2*)&Ws[kk][2 * tx];
      a00 = fma(av.x, wv2.x, a00); a01 = fma(av.x, wv2.y, a01);
      a10 = fma(av.y, wv2.x, a10); a11 = fma(av.y, wv2.y, a11);
    }
    __syncthreads();
  }
  const int r0 = row0 + 2 * ty, cc = col0 + 2 * tx;
  const double b0 = (double)qb1[cc], b1 = (double)qb1[cc + 1];
  double v00 = a00 + b0, v01 = a01 + b1, v10 = a10 + b0, v11 = a11 + b1;
  v00 = v00 > 0.0 ? v00 : expm1(v00);
  v01 = v01 > 0.0 ? v01 : expm1(v01);
  v10 = v10 > 0.0 ? v10 : expm1(v10);
  v11 = v11 > 0.0 ? v11 : expm1(v11);
  double* o = h1po + (size_t)r0 * 512 + cc;
  o[0] = v00; o[1] = v01; o[512] = v10; o[513] = v11;
}

// ---------------------------------------------------------------------------
// Kernel C: post logits = h1po @ qw2 + qb2 (f64), fused gumbel-argmax sample.
// Grid (32,8): each col-block = one class group s. Writes post-logits f32,
// one-hot stoch f32, and sidx/sval for next step's gather.
// ---------------------------------------------------------------------------
__global__ __launch_bounds__(256) void post2_k(const double* __restrict__ h1po,
                                               const float* __restrict__ qw2,
                                               const float* __restrict__ qb2,
                                               const uint32_t* __restrict__ keys,
                                               int* __restrict__ sidx,
                                               float* __restrict__ sval,
                                               float* __restrict__ out, int t) {
  __shared__ double As[16][34];
  __shared__ double Ws[16][32];
  __shared__ double Ls[32][33];
  __shared__ int bcS[32];
  const int tid = threadIdx.x;
  const int tx = tid & 15, ty = tid >> 4;
  const int row0 = blockIdx.y * 32;
  const int s = blockIdx.x;
  const int col0 = s * 32;
  double a00 = 0, a01 = 0, a10 = 0, a11 = 0;
  const int sA = tid * 2;
  const int kkA = sA & 15, mA = sA >> 4;
  const int kkW = sA >> 5, nW = sA & 31;
  for (int k0 = 0; k0 < 512; k0 += 16) {
    {
      const double2 dv = *(const double2*)(h1po + (size_t)(row0 + mA) * 512 + k0 + kkA);
      As[kkA][mA] = dv.x; As[kkA + 1][mA] = dv.y;
      const float2 wv = *(const float2*)(qw2 + (size_t)(k0 + kkW) * 1024 + col0 + nW);
      Ws[kkW][nW] = (double)wv.x; Ws[kkW][nW + 1] = (double)wv.y;
    }
    __syncthreads();
#pragma unroll
    for (int kk = 0; kk < 16; ++kk) {
      const double2 av = *(const double2*)&As[kk][2 * ty];
      const double2 wv2 = *(const double2*)&Ws[kk][2 * tx];
      a00 = fma(av.x, wv2.x, a00); a01 = fma(av.x, wv2.y, a01);
      a10 = fma(av.y, wv2.x, a10); a11 = fma(av.y, wv2.y, a11);
    }
    __syncthreads();
  }
  const uint32_t key0 = keys[2 * t], key1 = keys[2 * t + 1];
  double accv[2][2] = {{a00, a01}, {a10, a11}};
  for (int rb = 0; rb < 2; ++rb) {
    const int b = row0 + 2 * ty + rb;
    for (int cb = 0; cb < 2; ++cb) {
      const int col = col0 + 2 * tx + cb;
      const double l = accv[rb][cb] + (double)qb2[col];
      out[(size_t)b * OUT_ROW + (size_t)t * OUTFd + 2560 + col] = (float)l;
      // gumbel — EXACT round-1 formula (matches reference sampling bits)
      uint32_t o0, o1;
      tf2x32(key0, key1, 0u, (uint32_t)(b * 1024 + col), o0, o1);
      const uint32_t bits = o0 ^ o1;
      const uint32_t m = bits >> 9;
      const float uf = __uint_as_float(m | 0x3f800000u) - 1.0f;
      const double u = (m == 0u) ? (double)1.17549435e-38f : (double)uf;
      const double g = -log(-log(u));
      Ls[2 * ty + rb][2 * tx + cb] = l + g;
    }
  }
  __syncthreads();
  if (tid < 32) {
    const int bl = tid;
    double best = -1.0e300;
    int bc = 0;
    for (int c = 0; c < 32; ++c) {
      const double v = Ls[bl][c];
      if (v > best) { best = v; bc = c; }   // strict >: first-index ties
    }
    bcS[bl] = bc;
    const int b = row0 + bl;
    sidx[b * 32 + s] = bc;
    sval[b * 32 + s] = 1.0f;
  }
  __syncthreads();
  for (int rb = 0; rb < 2; ++rb) {
    const int b = row0 + 2 * ty + rb;
    const int bc = bcS[2 * ty + rb];
    for (int cb = 0; cb < 2; ++cb) {
      const int c = 2 * tx + cb;
      out[(size_t)b * OUT_ROW + (size_t)t * OUTFd + 512 + col0 + c] =
          (c == bc) ? 1.0f : 0.0f;
    }
  }
}

// ---------------------------------------------------------------------------
// Deferred prior head, f32, batched over (b, t) chunks of TC timesteps.
// prior1: h = ELU(deter @ pw1 + pb1)   [4096 x 512], deter read from d_out
// prior2: logits = h @ pw2 + pb2       [4096 x 1024] -> d_out prior block
// 64x64 tile, 256 threads, 4x4 per thread.
// ---------------------------------------------------------------------------
__global__ __launch_bounds__(256) void prior1_k(const float* __restrict__ outbase,
                                                const float* __restrict__ pw1,
                                                const float* __restrict__ pb1,
                                                float* __restrict__ hbuf, int tbase) {
  __shared__ float As[16][68];
  __shared__ float Ws[16][64];
  const int tid = threadIdx.x;
  const int tx = tid & 15, ty = tid >> 4;
  const int row0 = blockIdx.y * 64, col0 = blockIdx.x * 64;
  float acc[4][4] = {};
  const int sA = tid * 4;
  const int kkA = sA & 15, mA = sA >> 4;
  const int kkW = tid >> 4, nW = (tid & 15) * 4;
  const int grow = row0 + mA;
  const int b = grow >> 4, tt = tbase + (grow & 15);
  const float* arow = outbase + (size_t)b * OUT_ROW + (size_t)tt * OUTFd;
  for (int k0 = 0; k0 < 512; k0 += 16) {
    const float4 av = *(const float4*)(arow + k0 + kkA);
    As[kkA][mA] = av.x; As[kkA + 1][mA] = av.y;
    As[kkA + 2][mA] = av.z; As[kkA + 3][mA] = av.w;
    *(float4*)&Ws[kkW][nW] = *(const float4*)(pw1 + (size_t)(k0 + kkW) * 512 + col0 + nW);
    __syncthreads();
#pragma unroll
    for (int kk = 0; kk < 16; ++kk) {
      const float4 a = *(const float4*)&As[kk][4 * ty];
      const float4 w = *(const float4*)&Ws[kk][4 * tx];
      const float aa[4] = {a.x, a.y, a.z, a.w};
      const float ww[4] = {w.x, w.y, w.z, w.w};
#pragma unroll
      for (int i = 0; i < 4; ++i)
#pragma unroll
        for (int j = 0; j < 4; ++j) acc[i][j] = fmaf(aa[i], ww[j], acc[i][j]);
    }
    __syncthreads();
  }
#pragma unroll
  for (int i = 0; i < 4; ++i) {
    const int r = row0 + 4 * ty + i;
#pragma unroll
    for (int j = 0; j < 4; ++j) {
      const int c = col0 + 4 * tx + j;
      float x = acc[i][j] + pb1[c];
      x = x > 0.f ? x : expm1f(x);
      hbuf[(size_t)r * 512 + c] = x;
    }
  }
}

__global__ __launch_bounds__(256) void prior2_k(const float* __restrict__ hbuf,
                                                const float* __restrict__ pw2,
                                                const float* __restrict__ pb2,
                                                float* __restrict__ outbase, int tbase) {
  __shared__ float As[16][68];
  __shared__ float Ws[16][64];
  const int tid = threadIdx.x;
  const int tx = tid & 15, ty = tid >> 4;
  const int row0 = blockIdx.y * 64, col0 = blockIdx.x * 64;
  float acc[4][4] = {};
  const int sA = tid * 4;
  const int kkA = sA & 15, mA = sA >> 4;
  const int kkW = tid >> 4, nW = (tid & 15) * 4;
  for (int k0 = 0; k0 < 512; k0 += 16) {
    const float4 av = *(const float4*)(hbuf + (size_t)(row0 + mA) * 512 + k0 + kkA);
    As[kkA][mA] = av.x; As[kkA + 1][mA] = av.y;
    As[kkA + 2][mA] = av.z; As[kkA + 3][mA] = av.w;
    *(float4*)&Ws[kkW][nW] = *(const float4*)(pw2 + (size_t)(k0 + kkW) * 1024 + col0 + nW);
    __syncthreads();
#pragma unroll
    for (int kk = 0; kk < 16; ++kk) {
      const float4 a = *(const float4*)&As[kk][4 * ty];
      const float4 w = *(const float4*)&Ws[kk][4 * tx];
      const float aa[4] = {a.x, a.y, a.z, a.w};
      const float ww[4] = {w.x, w.y, w.z, w.w};
#pragma unroll
      for (int i = 0; i < 4; ++i)
#pragma unroll
        for (int j = 0; j < 4; ++j) acc[i][j] = fmaf(aa[i], ww[j], acc[i][j]);
    }
    __syncthreads();
  }
#pragma unroll
  for (int i = 0; i < 4; ++i) {
    const int grow = row0 + 4 * ty + i;
    const int b = grow >> 4, tt = tbase + (grow & 15);
    float* orow = outbase + (size_t)b * OUT_ROW + (size_t)tt * OUTFd + 1536;
#pragma unroll
    for (int j = 0; j < 4; ++j) {
      const int c = col0 + 4 * tx + j;
      orow[c] = acc[i][j] + pb2[c];
    }
  }
}

// ---------------------------------------------------------------------------
extern "C" void kernel_launch(void* const* d_in, const int* in_sizes, int n_in,
                              void* d_out, int out_size, void* d_ws, size_t ws_size,
                              hipStream_t stream) {
  const float* obs  = (const float*)d_in[0];
  const float* act  = (const float*)d_in[1];
  const float* w_ih = (const float*)d_in[2];
  const float* w_hh = (const float*)d_in[3];
  const float* b_ih = (const float*)d_in[4];
  const float* b_hh = (const float*)d_in[5];
  const float* pw1  = (const float*)d_in[6];
  const float* pb1  = (const float*)d_in[7];
  const float* pw2  = (const float*)d_in[8];
  const float* pb2  = (const float*)d_in[9];
  const float* qw1  = (const float*)d_in[10];
  const float* qb1  = (const float*)d_in[11];
  const float* qw2  = (const float*)d_in[12];
  const float* qb2  = (const float*)d_in[13];
  float* out = (float*)d_out;
  char* ws = (char*)d_ws;

  // workspace layout
  double*   deterA = (double*)(ws + 0);                 // 1 MiB
  double*   deterB = (double*)(ws + (1u << 20));        // 1 MiB
  double*   h1po   = (double*)(ws + (2u << 20));        // 1 MiB
  int*      sidx   = (int*)(ws + (3u << 20));           // 32 KiB
  float*    sval   = (float*)(ws + (3u << 20) + 32768); // 32 KiB
  uint32_t* keys   = (uint32_t*)(ws + (3u << 20) + 65536); // 1 KiB
  float*    hbuf   = (float*)(ws + (4u << 20));         // 8 MiB (4096x512 f32)

  hipMemsetAsync(deterA, 0, 256 * 512 * 8, stream);
  hipMemsetAsync(sidx, 0, 256 * 32 * 4, stream);
  hipMemsetAsync(sval, 0, 256 * 32 * 4, stream);
  keys_k<<<1, 128, 0, stream>>>(keys);

  for (int t = 0; t < Tt; ++t) {
    double* dp = (t & 1) ? deterB : deterA;
    double* dn = (t & 1) ? deterA : deterB;
    gru_k<<<dim3(16, 8), 256, 0, stream>>>(dp, dn, sidx, sval, act, w_ih, w_hh,
                                           b_ih, b_hh, out, t);
    post1_k<<<dim3(16, 8), 256, 0, stream>>>(dn, obs, qw1, qb1, h1po, t);
    post2_k<<<dim3(32, 8), 256, 0, stream>>>(h1po, qw2, qb2, keys, sidx, sval, out, t);
  }

  // deferred prior head (f32), batched over 8 chunks of TC=16 timesteps
  for (int c = 0; c < Tt / TC; ++c) {
    prior1_k<<<dim3(8, 64), 256, 0, stream>>>(out, pw1, pb1, hbuf, c * TC);
    prior2_k<<<dim3(16, 64), 256, 0, stream>>>(hbuf, pw2, pb2, out, c * TC);
  }
}